// Round 1
// baseline (121.693 us; speedup 1.0000x reference)
//
#include <hip/hip_runtime.h>

#define TRAJ 50

typedef __attribute__((ext_vector_type(8))) short short8;
typedef __attribute__((ext_vector_type(4))) float f32x4;

#if defined(__has_builtin)
#if __has_builtin(__builtin_amdgcn_exp2f)
#define EXP2F(x) __builtin_amdgcn_exp2f(x)
#else
#define EXP2F(x) exp2f(x)
#endif
#if __has_builtin(__builtin_amdgcn_rcpf)
#define RCPF(x) __builtin_amdgcn_rcpf(x)
#else
#define RCPF(x) (1.0f/(x))
#endif
#else
#define EXP2F(x) exp2f(x)
#define RCPF(x) (1.0f/(x))
#endif

__device__ __forceinline__ float sigm(float x){
  return RCPF(1.0f + EXP2F(-1.44269504f * x));
}
__device__ __forceinline__ float tanh_(float x){
  // tanh(x) = 1 - 2/(1+e^{2x})
  return 1.0f - 2.0f * RCPF(1.0f + EXP2F(2.88539008f * x));
}
__device__ __forceinline__ unsigned short f2bf(float f){
  union { float f; unsigned u; } v; v.f = f;
  unsigned u = v.u;
  u += 0x7FFFu + ((u >> 16) & 1u);   // RNE
  return (unsigned short)(u >> 16);
}
__device__ __forceinline__ unsigned pk(unsigned short a, unsigned short b){
  return (unsigned)a | ((unsigned)b << 16);
}

#define MFMA16(A,B,C) __builtin_amdgcn_mfma_f32_16x16x32_bf16((A),(B),(C),0,0,0)

// Block = 64 rows, 4 waves, each wave owns 16 rows independently.
// gatesT = A_aug @ h_as_B:  A rows = gate index i (192 + inn tiles), K = 64 (h) + {wp0,wp1,1}.
__global__ __launch_bounds__(256, 2) void gru_actor_kernel(
    const float* __restrict__ x,
    const float* __restrict__ W1, const float* __restrict__ b1,
    const float* __restrict__ W2, const float* __restrict__ b2,
    const float* __restrict__ Wih, const float* __restrict__ bih,
    const float* __restrict__ Whh, const float* __restrict__ bhh,
    const float* __restrict__ Wout, const float* __restrict__ bout,
    float* __restrict__ out)
{
  __shared__ __align__(16) char sm_a[32768];   // x tile [64][512B] -> h buffer [64][128B]
  __shared__ __align__(16) char sm_w[24576];   // W1T-half(16K)+W2T(8K) -> WhhT [192][128B]
  __shared__ float sm_b1[64];
  __shared__ float sm_b2[64];

  const int t    = threadIdx.x;
  const int row0 = blockIdx.x * 64;
  const int w    = t >> 6;
  const int l    = t & 63;
  const int lr   = l & 15;
  const int lg   = l >> 4;
  const int wrow = w * 16;
  const int myrow = wrow + lr;
  const int swz  = (myrow & 7) << 4;

  // ---------- stage x tile (f32 -> bf16, swizzled rows of 512B) ----------
  {
    const float4* xg = (const float4*)(x + (size_t)row0 * 256);
    #pragma unroll
    for (int it = 0; it < 16; ++it){
      int fi = t + it * 256;
      float4 v = xg[fi];
      int e = fi * 4;
      int row = e >> 8, col = e & 255;
      unsigned p0 = pk(f2bf(v.x), f2bf(v.y));
      unsigned p1 = pk(f2bf(v.z), f2bf(v.w));
      *(uint2*)(sm_a + row * 512 + ((col * 2) ^ ((row & 7) << 4))) = make_uint2(p0, p1);
    }
  }
  // ---------- stage W1T half 0: [i<64][k<128] bf16, stride 256B ----------
  for (int n = t; n < 8192; n += 256){
    int i = n & 63, kk = n >> 6;
    *(unsigned short*)(sm_w + i * 256 + ((kk * 2) ^ ((i & 7) << 4))) = f2bf(W1[kk * 64 + i]);
  }
  // ---------- stage W2T: [64][64] bf16, stride 128B at +16384 ----------
  for (int n = t; n < 4096; n += 256){
    int i = n & 63, kk = n >> 6;
    *(unsigned short*)(sm_w + 16384 + i * 128 + ((kk * 2) ^ ((i & 7) << 4))) = f2bf(W2[kk * 64 + i]);
  }
  if (t < 64){ sm_b1[t] = b1[t]; sm_b2[t] = b2[t]; }
  __syncthreads();

  // ---------- layer 1: z1^T = relu(W1^T @ x^T + b1), K=256 in two halves ----------
  f32x4 accL[4];
  #pragma unroll
  for (int T = 0; T < 4; ++T){
    const float4 bv = *(const float4*)(sm_b1 + 16 * T + lg * 4);
    accL[T] = (f32x4){bv.x, bv.y, bv.z, bv.w};
  }
  #pragma unroll
  for (int kb = 0; kb < 4; ++kb){
    short8 B = *(const short8*)(sm_a + myrow * 512 + ((kb * 64 + lg * 16) ^ swz));
    #pragma unroll
    for (int T = 0; T < 4; ++T){
      int ai = 16 * T + lr;
      short8 A = *(const short8*)(sm_w + ai * 256 + ((kb * 64 + lg * 16) ^ ((ai & 7) << 4)));
      accL[T] = MFMA16(A, B, accL[T]);
    }
  }
  __syncthreads();                       // done reading W1T half0
  for (int n = t; n < 8192; n += 256){   // restage half1 (k=128..255)
    int i = n & 63, kk = n >> 6;
    *(unsigned short*)(sm_w + i * 256 + ((kk * 2) ^ ((i & 7) << 4))) = f2bf(W1[(128 + kk) * 64 + i]);
  }
  __syncthreads();
  #pragma unroll
  for (int kb = 0; kb < 4; ++kb){
    short8 B = *(const short8*)(sm_a + myrow * 512 + (((kb + 4) * 64 + lg * 16) ^ swz));
    #pragma unroll
    for (int T = 0; T < 4; ++T){
      int ai = 16 * T + lr;
      short8 A = *(const short8*)(sm_w + ai * 256 + ((kb * 64 + lg * 16) ^ ((ai & 7) << 4)));
      accL[T] = MFMA16(A, B, accL[T]);
    }
  }
  __syncthreads();   // all waves done with x tile + W1T

  // ---------- z1 -> h buffer region (aliases x tile, rows of 128B) ----------
  #pragma unroll
  for (int T = 0; T < 4; ++T){
    f32x4 a = accL[T];
    unsigned p0 = pk(f2bf(fmaxf(a[0],0.f)), f2bf(fmaxf(a[1],0.f)));
    unsigned p1 = pk(f2bf(fmaxf(a[2],0.f)), f2bf(fmaxf(a[3],0.f)));
    int ib = (16 * T + lg * 4) * 2;
    *(uint2*)(sm_a + myrow * 128 + (ib ^ swz)) = make_uint2(p0, p1);
  }
  // ---------- layer 2: z2^T = relu(W2^T @ z1^T + b2) ----------
  f32x4 acc2[4];
  #pragma unroll
  for (int T = 0; T < 4; ++T){
    const float4 bv = *(const float4*)(sm_b2 + 16 * T + lg * 4);
    acc2[T] = (f32x4){bv.x, bv.y, bv.z, bv.w};
  }
  #pragma unroll
  for (int kb = 0; kb < 2; ++kb){
    short8 B = *(const short8*)(sm_a + myrow * 128 + ((kb * 64 + lg * 16) ^ swz));
    #pragma unroll
    for (int T = 0; T < 4; ++T){
      int ai = 16 * T + lr;
      short8 A = *(const short8*)(sm_w + 16384 + ai * 128 + ((kb * 64 + lg * 16) ^ ((ai & 7) << 4)));
      acc2[T] = MFMA16(A, B, acc2[T]);
    }
  }
  float h[16];
  #pragma unroll
  for (int T = 0; T < 4; ++T){
    f32x4 a = acc2[T];
    #pragma unroll
    for (int r = 0; r < 4; ++r) h[4*T+r] = fmaxf(a[r], 0.f);
    unsigned p0 = pk(f2bf(h[4*T+0]), f2bf(h[4*T+1]));
    unsigned p1 = pk(f2bf(h[4*T+2]), f2bf(h[4*T+3]));
    int ib = (16 * T + lg * 4) * 2;
    *(uint2*)(sm_a + myrow * 128 + (ib ^ swz)) = make_uint2(p0, p1);
  }
  __syncthreads();   // all waves done with W2T region

  // ---------- stage WhhT [i<192][k<64] bf16, stride 128B over all of sm_w ----------
  for (int n = t; n < 12288; n += 256){
    int kk = n / 192;
    int i  = n - kk * 192;
    *(unsigned short*)(sm_w + i * 128 + ((kk * 2) ^ ((i & 7) << 4))) = f2bf(Whh[kk * 192 + i]);
  }
  __syncthreads();

  // ---------- preload loop-invariant A fragments ----------
  short8 Ah[12][2];                 // Whh^T, k-blocks 0,1 (k=0..63)
  #pragma unroll
  for (int T = 0; T < 12; ++T){
    int i = 16 * T + lr;
    #pragma unroll
    for (int kb = 0; kb < 2; ++kb)
      Ah[T][kb] = *(const short8*)(sm_w + i * 128 + ((kb * 64 + lg * 16) ^ ((i & 7) << 4)));
  }
  short8 Ak2[16];                   // augmented k-block 2: k=64(wp0),65(wp1),66(1.0)
  #pragma unroll
  for (int T = 0; T < 16; ++T){
    short8 f = (short8){0,0,0,0,0,0,0,0};
    if (lg == 0){
      float v0 = 0.f, v1 = 0.f, v2 = 0.f;
      if (T < 8){ int i = 16*T + lr; v0 = Wih[i]; v1 = Wih[192 + i]; v2 = bih[i] + bhh[i]; } // r,u: full fold
      else if (T < 12){ int i = 16*T + lr; v2 = bhh[i]; }                                    // hn: bhh only
      else { int i = 128 + 16*(T-12) + lr; v0 = Wih[i]; v1 = Wih[192 + i]; v2 = bih[i]; }    // inn
      f[0] = (short)f2bf(v0); f[1] = (short)f2bf(v1); f[2] = (short)f2bf(v2);
    }
    Ak2[T] = f;
  }
  short8 Aout[2];                   // Wout^T rows 0,1
  #pragma unroll
  for (int kb = 0; kb < 2; ++kb){
    short8 f = (short8){0,0,0,0,0,0,0,0};
    if (lr < 2){
      #pragma unroll
      for (int j = 0; j < 8; ++j){
        int k = kb * 32 + lg * 8 + j;
        f[j] = (short)f2bf(Wout[k * 2 + lr]);
      }
    }
    Aout[kb] = f;
  }
  const float bo0 = bout[0], bo1 = bout[1];

  // ---------- GRU rollout (waves fully independent; no barriers) ----------
  float wp0 = 0.f, wp1 = 0.f;
  float* outp = out + (size_t)(row0 + myrow) * 100;

  short8 B0 = *(const short8*)(sm_a + myrow * 128 + ((lg * 16) ^ swz));
  short8 B1 = *(const short8*)(sm_a + myrow * 128 + ((64 + lg * 16) ^ swz));

  #pragma unroll 1
  for (int s = 0; s < TRAJ; ++s){
    short8 B2 = (short8){0,0,0,0,0,0,0,0};
    if (lg == 0){
      B2[0] = (short)f2bf(wp0);
      B2[1] = (short)f2bf(wp1);
      B2[2] = (short)0x3F80;     // 1.0 bf16
    }
    #pragma unroll
    for (int tq = 0; tq < 4; ++tq){
      f32x4 aR = (f32x4){0,0,0,0}, aU = (f32x4){0,0,0,0};
      f32x4 aN = (f32x4){0,0,0,0}, aI = (f32x4){0,0,0,0};
      aR = MFMA16(Ah[tq    ][0], B0, aR);
      aR = MFMA16(Ah[tq    ][1], B1, aR);
      aR = MFMA16(Ak2[tq    ],   B2, aR);
      aU = MFMA16(Ah[4 + tq][0], B0, aU);
      aU = MFMA16(Ah[4 + tq][1], B1, aU);
      aU = MFMA16(Ak2[4 + tq],   B2, aU);
      aN = MFMA16(Ah[8 + tq][0], B0, aN);
      aN = MFMA16(Ah[8 + tq][1], B1, aN);
      aN = MFMA16(Ak2[8 + tq],   B2, aN);
      aI = MFMA16(Ak2[12 + tq],  B2, aI);
      #pragma unroll
      for (int r = 0; r < 4; ++r){
        float rv = sigm(aR[r]);
        float uv = sigm(aU[r]);
        float nv = tanh_(aI[r] + rv * aN[r]);
        int idx = 4 * tq + r;
        h[idx] = (1.f - uv) * nv + uv * h[idx];
      }
      unsigned p0 = pk(f2bf(h[4*tq+0]), f2bf(h[4*tq+1]));
      unsigned p1 = pk(f2bf(h[4*tq+2]), f2bf(h[4*tq+3]));
      *(uint2*)(sm_a + myrow * 128 + (((16*tq + lg*4)*2) ^ swz)) = make_uint2(p0, p1);
    }
    // dx = sigmoid(h_new @ Wout + bout); reuse frags as next step's B0/B1
    short8 nB0 = *(const short8*)(sm_a + myrow * 128 + ((lg * 16) ^ swz));
    short8 nB1 = *(const short8*)(sm_a + myrow * 128 + ((64 + lg * 16) ^ swz));
    f32x4 aD = (f32x4){0,0,0,0};
    if (lg == 0){ aD[0] = bo0; aD[1] = bo1; }
    aD = MFMA16(Aout[0], nB0, aD);
    aD = MFMA16(Aout[1], nB1, aD);
    if (lg == 0){
      wp0 += sigm(aD[0]);
      wp1 += sigm(aD[1]);
      *(float2*)(outp + 2 * s) = make_float2(wp0, wp1);
    }
    B0 = nB0; B1 = nB1;
  }
}

extern "C" void kernel_launch(void* const* d_in, const int* in_sizes, int n_in,
                              void* d_out, int out_size, void* d_ws, size_t ws_size,
                              hipStream_t stream) {
  (void)n_in; (void)out_size; (void)d_ws; (void)ws_size;
  const float* x    = (const float*)d_in[0];
  const float* W1   = (const float*)d_in[1];
  const float* b1   = (const float*)d_in[2];
  const float* W2   = (const float*)d_in[3];
  const float* b2   = (const float*)d_in[4];
  const float* Wih  = (const float*)d_in[5];
  const float* bih  = (const float*)d_in[6];
  const float* Whh  = (const float*)d_in[7];
  const float* bhh  = (const float*)d_in[8];
  const float* Wout = (const float*)d_in[9];
  const float* bout = (const float*)d_in[10];
  float* out = (float*)d_out;

  int nrows = in_sizes[0] / 256;
  int grid  = nrows / 64;
  gru_actor_kernel<<<dim3(grid), dim3(256), 0, stream>>>(
      x, W1, b1, W2, b2, Wih, bih, Whh, bhh, Wout, bout, out);
}

// Round 2
// 117.655 us; speedup vs baseline: 1.0343x; 1.0343x over previous
//
#include <hip/hip_runtime.h>
#include <hip/hip_bf16.h>

#define TRAJ 50

typedef __attribute__((ext_vector_type(8))) short short8;
typedef __attribute__((ext_vector_type(4))) float f32x4;

#if defined(__has_builtin)
#if __has_builtin(__builtin_amdgcn_exp2f)
#define EXP2F(x) __builtin_amdgcn_exp2f(x)
#else
#define EXP2F(x) exp2f(x)
#endif
#if __has_builtin(__builtin_amdgcn_rcpf)
#define RCPF(x) __builtin_amdgcn_rcpf(x)
#else
#define RCPF(x) (1.0f/(x))
#endif
#else
#define EXP2F(x) exp2f(x)
#define RCPF(x) (1.0f/(x))
#endif

__device__ __forceinline__ unsigned short f2bf(float f){
  union { float f; unsigned u; } v; v.f = f;
  unsigned u = v.u;
  u += 0x7FFFu + ((u >> 16) & 1u);   // RNE
  return (unsigned short)(u >> 16);
}
__device__ __forceinline__ unsigned pk(unsigned short a, unsigned short b){
  return (unsigned)a | ((unsigned)b << 16);
}
__device__ __forceinline__ unsigned pkbf(float a, float b){
  union { __hip_bfloat162 h; unsigned u; } c;
  c.h = __float22bfloat162_rn(make_float2(a, b));   // v_cvt_pk_bf16_f32
  return c.u;
}
__device__ __forceinline__ short8 mkfrag(uint2 v){
  union { unsigned u[4]; short8 s; } c;
  c.u[0] = v.x; c.u[1] = v.y; c.u[2] = 0u; c.u[3] = 0u;
  return c.s;
}

#define MFMA16(A,B,C) __builtin_amdgcn_mfma_f32_16x16x32_bf16((A),(B),(C),0,0,0)

#define SSC (-1.44269504f)   // sigmoid scale: sigma(x) = 1/(1+2^(SSC*x))
#define TSC ( 2.88539008f)   // tanh scale:   tanh(y)  = 1-2/(1+2^(TSC*y))

// Block = 512 threads = 8 waves = 4 pairs; each pair owns 16 rows; wave p of a
// pair computes gate dims [32p, 32p+32). h exchanged via double-buffered LDS,
// one __syncthreads per rollout step. Gates computed as gates^T = A_aug @ h_B.
__global__ __launch_bounds__(512, 4) void gru_actor_kernel(
    const float* __restrict__ x,
    const float* __restrict__ W1, const float* __restrict__ b1,
    const float* __restrict__ W2, const float* __restrict__ b2,
    const float* __restrict__ Wih, const float* __restrict__ bih,
    const float* __restrict__ Whh, const float* __restrict__ bhh,
    const float* __restrict__ Wout, const float* __restrict__ bout,
    float* __restrict__ out)
{
  __shared__ __align__(16) char sm_x[32768];   // x tile [64][512B]; h0 = +0 (8KB), h1 = +8192 (8KB)
  __shared__ __align__(16) char sm_w[32768];   // W1T full [64][512B] -> WhhT [192][128B] (pre-scaled)
  __shared__ __align__(16) char sm_w2[8192];   // W2T [64][128B]
  __shared__ __align__(16) char sm_wo[2048];   // WoutT-scaled [16][128B] (rows 2..15 zero)
  __shared__ float sm_b1[64];
  __shared__ float sm_b2[64];

  const int t    = threadIdx.x;        // 0..511
  const int row0 = blockIdx.x * 64;
  const int w    = t >> 6;             // wave 0..7
  const int pair = w >> 1;             // 0..3
  const int p    = w & 1;              // dim-half of the pair
  const int l    = t & 63;
  const int lr   = l & 15;
  const int lg   = l >> 4;
  const int myrow = pair * 16 + lr;    // 0..63
  const int swz  = (lr & 7) << 4;      // (myrow&7)==(lr&7); also == A-row swizzle

  // ---------------- stage x (f32 -> bf16, [64][512B] swizzled) ----------------
  {
    const float4* xg = (const float4*)(x + (size_t)row0 * 256);
    #pragma unroll
    for (int it = 0; it < 8; ++it){
      int fi = t + it * 512;
      float4 v = xg[fi];
      int e = fi * 4, row = e >> 8, col = e & 255;
      *(uint2*)(sm_x + row * 512 + ((col * 2) ^ ((row & 7) << 4))) =
          make_uint2(pkbf(v.x, v.y), pkbf(v.z, v.w));
    }
  }
  // W1T full: [i<64][k<256] bf16, stride 512B
  for (int n = t; n < 16384; n += 512){
    int i = n & 63, kk = n >> 6;
    *(unsigned short*)(sm_w + i * 512 + ((kk * 2) ^ ((i & 7) << 4))) = f2bf(W1[kk * 64 + i]);
  }
  // W2T: [64][64] bf16, stride 128B
  for (int n = t; n < 4096; n += 512){
    int i = n & 63, kk = n >> 6;
    *(unsigned short*)(sm_w2 + i * 128 + ((kk * 2) ^ ((i & 7) << 4))) = f2bf(W2[kk * 64 + i]);
  }
  // WoutT scaled: rows 0,1 = SSC*Wout col; rows 2..15 zero (A-frag needs clean zeros)
  for (int n = t; n < 1024; n += 512){
    int row = n & 15, k = n >> 4;
    float v = (row < 2) ? SSC * Wout[k * 2 + row] : 0.0f;
    *(unsigned short*)(sm_wo + row * 128 + k * 2) = f2bf(v);
  }
  if (t < 64){ sm_b1[t] = b1[t]; sm_b2[t] = b2[t]; }
  __syncthreads();                                   // B1: staging done

  // ---------------- layer 1: z1^T = relu(W1T @ xT + b1), wave does tiles 2p,2p+1 ----------------
  const int ar0 = 16 * (2 * p + 0) + lr;   // W-row for tile a  ((ar&7)==(lr&7))
  const int ar1 = 16 * (2 * p + 1) + lr;
  f32x4 accL0, accL1;
  {
    float4 bva = *(const float4*)(sm_b1 + 16 * (2 * p + 0) + lg * 4);
    float4 bvb = *(const float4*)(sm_b1 + 16 * (2 * p + 1) + lg * 4);
    accL0 = (f32x4){bva.x, bva.y, bva.z, bva.w};
    accL1 = (f32x4){bvb.x, bvb.y, bvb.z, bvb.w};
  }
  #pragma unroll
  for (int kb = 0; kb < 8; ++kb){
    short8 B  = *(const short8*)(sm_x + myrow * 512 + ((kb * 64 + lg * 16) ^ swz));
    short8 Aa = *(const short8*)(sm_w + ar0 * 512 + ((kb * 64 + lg * 16) ^ swz));
    short8 Ab = *(const short8*)(sm_w + ar1 * 512 + ((kb * 64 + lg * 16) ^ swz));
    accL0 = MFMA16(Aa, B, accL0);
    accL1 = MFMA16(Ab, B, accL1);
  }
  __syncthreads();                                   // B2: all x/W1T reads done

  // write z1 (bf16) into h0 region (aliases x tile); stage WhhT (aliases W1T, pre-scaled)
  {
    f32x4 a0 = accL0, a1 = accL1;
    *(uint2*)(sm_x + myrow * 128 + ((64 * p + 0  + 8 * lg) ^ swz)) =
        make_uint2(pkbf(fmaxf(a0[0],0.f), fmaxf(a0[1],0.f)), pkbf(fmaxf(a0[2],0.f), fmaxf(a0[3],0.f)));
    *(uint2*)(sm_x + myrow * 128 + ((64 * p + 32 + 8 * lg) ^ swz)) =
        make_uint2(pkbf(fmaxf(a1[0],0.f), fmaxf(a1[1],0.f)), pkbf(fmaxf(a1[2],0.f), fmaxf(a1[3],0.f)));
  }
  for (int n = t; n < 12288; n += 512){
    int kk = n / 192, i = n - kk * 192;
    float s = (i < 128) ? SSC : TSC;   // r,u rows scaled by SSC; n rows by TSC
    *(unsigned short*)(sm_w + i * 128 + ((kk * 2) ^ ((i & 7) << 4))) = f2bf(s * Whh[kk * 192 + i]);
  }
  __syncthreads();                                   // B3: z1 + WhhT ready

  // ---------------- layer 2: h = relu(W2T @ z1T + b2) ----------------
  float h[8];
  {
    f32x4 acc20, acc21;
    float4 bva = *(const float4*)(sm_b2 + 16 * (2 * p + 0) + lg * 4);
    float4 bvb = *(const float4*)(sm_b2 + 16 * (2 * p + 1) + lg * 4);
    acc20 = (f32x4){bva.x, bva.y, bva.z, bva.w};
    acc21 = (f32x4){bvb.x, bvb.y, bvb.z, bvb.w};
    #pragma unroll
    for (int kb = 0; kb < 2; ++kb){
      short8 B  = *(const short8*)(sm_x + myrow * 128 + ((kb * 64 + lg * 16) ^ swz));
      short8 Aa = *(const short8*)(sm_w2 + ar0 * 128 + ((kb * 64 + lg * 16) ^ swz));
      short8 Ab = *(const short8*)(sm_w2 + ar1 * 128 + ((kb * 64 + lg * 16) ^ swz));
      acc20 = MFMA16(Aa, B, acc20);
      acc21 = MFMA16(Ab, B, acc21);
    }
    #pragma unroll
    for (int r = 0; r < 4; ++r){ h[r] = fmaxf(acc20[r], 0.f); h[4 + r] = fmaxf(acc21[r], 0.f); }
    *(uint2*)(sm_x + 8192 + myrow * 128 + ((64 * p + 0  + 8 * lg) ^ swz)) =
        make_uint2(pkbf(h[0], h[1]), pkbf(h[2], h[3]));
    *(uint2*)(sm_x + 8192 + myrow * 128 + ((64 * p + 32 + 8 * lg) ^ swz)) =
        make_uint2(pkbf(h[4], h[5]), pkbf(h[6], h[7]));
  }

  // ---------------- preload loop-invariant fragments ----------------
  short8 Ah[3][2][2];    // [gate r/u/n][tql][kb]: WhhT rows (pre-scaled)
  #pragma unroll
  for (int g = 0; g < 3; ++g){
    #pragma unroll
    for (int tql = 0; tql < 2; ++tql){
      int i = g * 64 + 32 * p + 16 * tql + lr;
      #pragma unroll
      for (int kb = 0; kb < 2; ++kb)
        Ah[g][tql][kb] = *(const short8*)(sm_w + i * 128 + ((kb * 64 + lg * 16) ^ swz));
    }
  }
  // augmented k-block (k=64:wp0, 65:wp1, 66:1.0) -> only lg==0 lanes nonzero; packed uint2
  uint2 Ak2p[4][2] = {};   // [r,u,hn,inn][tql]
  if (lg == 0){
    #pragma unroll
    for (int tql = 0; tql < 2; ++tql){
      int dr = 32 * p + 16 * tql + lr;
      int du = 64 + dr, dn = 128 + dr;
      Ak2p[0][tql] = make_uint2(pk(f2bf(SSC*Wih[dr]), f2bf(SSC*Wih[192+dr])),
                                pk(f2bf(SSC*(bih[dr]+bhh[dr])), 0));
      Ak2p[1][tql] = make_uint2(pk(f2bf(SSC*Wih[du]), f2bf(SSC*Wih[192+du])),
                                pk(f2bf(SSC*(bih[du]+bhh[du])), 0));
      Ak2p[2][tql] = make_uint2(0u, pk(f2bf(TSC*bhh[dn]), 0));
      Ak2p[3][tql] = make_uint2(pk(f2bf(TSC*Wih[dn]), f2bf(TSC*Wih[192+dn])),
                                pk(f2bf(TSC*bih[dn]), 0));
    }
  }
  const float bo0 = SSC * bout[0], bo1 = SSC * bout[1];
  __syncthreads();                                   // B4: h(buf1) ready

  // ---------------- GRU rollout: 1 barrier/step, h double-buffered ----------------
  float wp0 = 0.f, wp1 = 0.f;
  float* outp = out + (size_t)(row0 + myrow) * 100;
  short8 B0 = *(const short8*)(sm_x + 8192 + myrow * 128 + ((0  + lg * 16) ^ swz));
  short8 B1 = *(const short8*)(sm_x + 8192 + myrow * 128 + ((64 + lg * 16) ^ swz));

  #pragma unroll 1
  for (int s = 0; s < TRAJ; ++s){
    char* bufW = sm_x + ((s & 1) << 13);   // step0 writes h0, step1 h1, ...
    short8 B2;
    {
      unsigned b2lo = 0u, b2hi = 0u;
      if (lg == 0){ b2lo = pkbf(wp0, wp1); b2hi = 0x00003F80u; }   // f[2] = 1.0bf
      union { unsigned u[4]; short8 sv; } c;
      c.u[0] = b2lo; c.u[1] = b2hi; c.u[2] = 0u; c.u[3] = 0u;
      B2 = c.sv;
    }
    #pragma unroll
    for (int tql = 0; tql < 2; ++tql){
      f32x4 aR = (f32x4){0,0,0,0}, aU = (f32x4){0,0,0,0};
      f32x4 aN = (f32x4){0,0,0,0}, aI = (f32x4){0,0,0,0};
      aR = MFMA16(Ah[0][tql][0], B0, aR);
      aR = MFMA16(Ah[0][tql][1], B1, aR);
      aR = MFMA16(mkfrag(Ak2p[0][tql]), B2, aR);
      aU = MFMA16(Ah[1][tql][0], B0, aU);
      aU = MFMA16(Ah[1][tql][1], B1, aU);
      aU = MFMA16(mkfrag(Ak2p[1][tql]), B2, aU);
      aN = MFMA16(Ah[2][tql][0], B0, aN);
      aN = MFMA16(Ah[2][tql][1], B1, aN);
      aN = MFMA16(mkfrag(Ak2p[2][tql]), B2, aN);
      aI = MFMA16(mkfrag(Ak2p[3][tql]), B2, aI);
      #pragma unroll
      for (int r = 0; r < 4; ++r){
        float e1 = EXP2F(aR[r]);               // pre-scaled: = 2^(-1.4427*arg_r)
        float e2 = EXP2F(aU[r]);
        float d1 = 1.f + e1, d2 = 1.f + e2;
        float rp = RCPF(d1 * d2);              // shared rcp for r,u
        float rv = d2 * rp;                    // sigma(arg_r)
        float uv = d1 * rp;                    // sigma(arg_u)
        float y  = fmaf(rv, aN[r], aI[r]);     // = TSC*(inn + r*hn)
        float nv = fmaf(-2.f, RCPF(1.f + EXP2F(y)), 1.f);   // tanh
        int hi_ = 4 * tql + r;
        h[hi_] = fmaf(uv, h[hi_] - nv, nv);
      }
      *(uint2*)(bufW + myrow * 128 + ((64 * p + 32 * tql + 8 * lg) ^ swz)) =
          make_uint2(pkbf(h[4*tql+0], h[4*tql+1]), pkbf(h[4*tql+2], h[4*tql+3]));
    }
    __syncthreads();
    short8 nB0 = *(const short8*)(bufW + myrow * 128 + ((0  + lg * 16) ^ swz));
    short8 nB1 = *(const short8*)(bufW + myrow * 128 + ((64 + lg * 16) ^ swz));
    short8 Ao0 = *(const short8*)(sm_wo + lr * 128 + 0  + lg * 16);
    short8 Ao1 = *(const short8*)(sm_wo + lr * 128 + 64 + lg * 16);
    f32x4 aD = (f32x4){0,0,0,0};
    if (lg == 0){ aD[0] = bo0; aD[1] = bo1; }
    aD = MFMA16(Ao0, nB0, aD);
    aD = MFMA16(Ao1, nB1, aD);
    if (lg == 0){
      float ea = EXP2F(aD[0]), eb = EXP2F(aD[1]);
      float da = 1.f + ea, db = 1.f + eb;
      float rp = RCPF(da * db);
      wp0 += db * rp;                          // sigmoid(dx0)
      wp1 += da * rp;                          // sigmoid(dx1)
      if (p == 0) *(float2*)(outp + 2 * s) = make_float2(wp0, wp1);
    }
    B0 = nB0; B1 = nB1;
  }
}

extern "C" void kernel_launch(void* const* d_in, const int* in_sizes, int n_in,
                              void* d_out, int out_size, void* d_ws, size_t ws_size,
                              hipStream_t stream) {
  (void)n_in; (void)out_size; (void)d_ws; (void)ws_size;
  const float* x    = (const float*)d_in[0];
  const float* W1   = (const float*)d_in[1];
  const float* b1   = (const float*)d_in[2];
  const float* W2   = (const float*)d_in[3];
  const float* b2   = (const float*)d_in[4];
  const float* Wih  = (const float*)d_in[5];
  const float* bih  = (const float*)d_in[6];
  const float* Whh  = (const float*)d_in[7];
  const float* bhh  = (const float*)d_in[8];
  const float* Wout = (const float*)d_in[9];
  const float* bout = (const float*)d_in[10];
  float* out = (float*)d_out;

  int nrows = in_sizes[0] / 256;
  int grid  = nrows / 64;
  gru_actor_kernel<<<dim3(grid), dim3(512), 0, stream>>>(
      x, W1, b1, W2, b2, Wih, bih, Whh, bhh, Wout, bout, out);
}